// Round 10
// baseline (629.578 us; speedup 1.0000x reference)
//
#include <hip/hip_runtime.h>

#define D_  256
#define K_  1024
#define HW_ 1024      // 32*32
#define N_  32768     // 32*HW_

// workspace layout (bytes)
#define WS_COUNTS  262144     // f32[1024]
#define WS_EMBSUM  266240     // f32[262144]
#define WS_LOSS    1314816    // f32
#define WS_NSUM    1314820    // f32
#define WS_ENMAX   1314824    // u32 (max ||e||^2 bits)
#define WS_ZERO0   262144     // zero range start
#define WS_ZEROLEN 1052684    // covers counts..enmax
#define WS_NEWCS   1314828    // f32[1024]
#define WS_ENORM   1318924    // f32[1024]
#define WS_E16     1454096    // fp16(512*E)[1024*256] = 512 KiB (16B aligned)
#define WS_TOTAL   1978384

// output offsets (f32 elements): (z_q_st, loss, indices, new_emb, new_cs, new_es)
#define O_ZQ   0
#define O_LOSS 8388608
#define O_IDX  8388609
#define O_EMB  8421377
#define O_NCS  8683521
#define O_NES  8684545

typedef unsigned short u16;
typedef _Float16 f16x8 __attribute__((ext_vector_type(8)));  // 8 f16 = 4 VGPRs
typedef float f32x4 __attribute__((ext_vector_type(4)));

// pack two f32 -> two f16 (HW v_cvt_f16_f32, rne)
__device__ __forceinline__ unsigned f16x2pack(float a, float b) {
  union { _Float16 h; unsigned short u; } ca, cb;
  ca.h = (_Float16)a; cb.h = (_Float16)b;
  return (unsigned)ca.u | ((unsigned)cb.u << 16);
}

// numpy pairwise_sum of 256 squares: two 128-halves, 8 accumulators,
// combine ((r0+r1)+(r2+r3))+((r4+r5)+(r6+r7)). __f*_rn blocks FMA contraction.
__device__ __forceinline__ float pw256_sq(const float* __restrict__ p, int stride) {
  float tot0 = 0.f, tot1 = 0.f;
#pragma unroll
  for (int h = 0; h < 2; ++h) {
    const float* q = p + h * 128 * stride;
    float r[8];
#pragma unroll
    for (int j = 0; j < 8; ++j) { float x = q[j * stride]; r[j] = __fmul_rn(x, x); }
    for (int i = 8; i < 128; i += 8)
#pragma unroll
      for (int j = 0; j < 8; ++j) {
        float x = q[(i + j) * stride];
        r[j] = __fadd_rn(r[j], __fmul_rn(x, x));
      }
    float s = __fadd_rn(__fadd_rn(__fadd_rn(r[0], r[1]), __fadd_rn(r[2], r[3])),
                        __fadd_rn(__fadd_rn(r[4], r[5]), __fadd_rn(r[6], r[7])));
    if (h == 0) tot0 = s; else tot1 = s;
  }
  return __fadd_rn(tot0, tot1);
}

// ---------------- E prep: ||e||^2 (np order), en_max, E->fp16*512 ----------------
// 32 blocks (round-9 had 4: conversion ran on 4 CUs only).
__global__ void vq_eprep(const float* __restrict__ E, float* __restrict__ enorm,
                         u16* __restrict__ E16, unsigned* __restrict__ enmax) {
  int gid = blockIdx.x * 256 + threadIdx.x;   // 0..8191
  if (gid < K_) {
    float v = pw256_sq(E + gid * D_, 1);
    enorm[gid] = v;
    atomicMax(enmax, __float_as_uint(v));     // v > 0 -> bit-monotone
  }
  unsigned* E16w = (unsigned*)E16;
  for (int wd = gid; wd < (K_ * D_ / 2); wd += 8192) {
    float2 x = *(const float2*)(E + 2 * wd);
    E16w[wd] = f16x2pack(512.0f * x.x, 512.0f * x.y);
  }
}

// VALU-speed 16-lane min via DPP (quad_perm ^1, ^2, row_half_mirror, row_mirror)
template <int CTRL>
__device__ __forceinline__ float dppmin(float v) {
  int p = __builtin_amdgcn_update_dpp(0, __float_as_int(v), CTRL, 0xF, 0xF, true);
  return fminf(v, __int_as_float(p));
}

// Exact reference-numerics distance (np-order sequential fp32 FMA over d, then
// fl(fl(zn-2a)+en)); z row strided from GLOBAL (L1/L2-hot: staged moments ago),
// E row via float4. Key=(score_bits<<32)|code -> LDS u64 atomicMin (block-final
// best; lowest code wins ties = np argmin). Called only AFTER the MFMA loop.
__device__ __forceinline__ void exact_update(
    const float* __restrict__ zb, const float* __restrict__ E, int t, int c,
    const float* zn_s, const float* en_s, unsigned long long* best_s) {
  const float* zp = zb + t;             // stride HW_ over d (original f32 z)
  const float* ep = E + c * D_;
  float a = 0.f;
  for (int d0 = 0; d0 < 256; d0 += 8) {
    float zr[8];
#pragma unroll
    for (int j = 0; j < 8; ++j) zr[j] = zp[(d0 + j) * HW_];
    float4 e0 = *(const float4*)(ep + d0);
    float4 e1 = *(const float4*)(ep + d0 + 4);
    a = __fmaf_rn(zr[0], e0.x, a); a = __fmaf_rn(zr[1], e0.y, a);
    a = __fmaf_rn(zr[2], e0.z, a); a = __fmaf_rn(zr[3], e0.w, a);
    a = __fmaf_rn(zr[4], e1.x, a); a = __fmaf_rn(zr[5], e1.y, a);
    a = __fmaf_rn(zr[6], e1.z, a); a = __fmaf_rn(zr[7], e1.w, a);
  }
  float s = __fadd_rn(__fsub_rn(zn_s[t], __fmul_rn(2.0f, a)), en_s[c]);
  unsigned long long key = ((unsigned long long)__float_as_uint(s) << 32) | (unsigned)c;
  atomicMin(&best_s[t], key);
}

#define TCAP 96   // per-wave trigger list (expected ~24 used w/ fp16 margin)

// ---------------- FUSED dist + scatter, 64-token geometry ----------------
// 512 blocks x 512 thr (8 waves), 2 blocks/CU (one round). Block = 64 tokens x
// ALL 1024 codes => best block-final => scatter fused. Round-10 changes vs r9:
//  - 64-tok blocks: E16 L2 traffic halved (r8's 32-tok dist was 110us vs r5's
//    64-tok 86us — geometry, not occupancy, was the regression).
//  - fp16 LDS tile in r8's conflict-free [kb][tok][8d] layout; no in-loop cvt
//    (r9's f32 tile: 6.26M bank conflicts + 16 cvt/step).
//  - no f32 LDS tile at all: znorm + exact-verify + phase B read z from global
//    (tile-local, L1/L2-hot; candidates are only ~24/wave now).
// fp16 MFMA (z f16, E f16*512) -> ph = en - 2*(A/512); margin
// M = 2^-8*sqrt(zn*en_max)+5e-4 (2x the rigorous two-sided fp16 bound) ->
// reference argmin always triggers; exact fp32 chain (np order) decides.
__global__ __launch_bounds__(512, 4) void vq_main(
    const float* __restrict__ z, const float* __restrict__ E,
    const u16* __restrict__ E16, const float* __restrict__ enorm,
    const unsigned* __restrict__ enmax,
    float* __restrict__ embsum, float* __restrict__ loss_sum,
    float* __restrict__ counts, float* __restrict__ out_zq,
    float* __restrict__ out_idx) {
  __shared__ __align__(16) u16 zt[32 * 64 * 8];          // 32 KiB, [kb][tok][8d]
  __shared__ float en_s[K_];                              // 4 KiB
  __shared__ float zn_s[64];
  __shared__ float mg_s[64];
  __shared__ unsigned rmin_s[64];                         // bits of (min ph)+4.0
  __shared__ unsigned long long best_s[64];
  __shared__ unsigned tcount[8];
  __shared__ unsigned tlist[8][TCAP];                     // 3 KiB
  __shared__ float wred[8];

  const int tid = threadIdx.x;
  const int tile = blockIdx.x;               // 0..511
  const int bimg = tile >> 4;
  const int hw0 = (tile & 15) << 6;          // 64 tokens
  const float* zb = z + bimg * (D_ * HW_) + hw0;
  const int n0 = bimg * HW_ + hw0;

  if (tid < 64) {
    float zn = pw256_sq(zb + tid, HW_);      // np order, global strided (L2-hot)
    zn_s[tid] = zn;
    float em = __uint_as_float(*enmax);
    mg_s[tid] = 0.00390625f * sqrtf(zn * em) + 5e-4f;  // fp16 margin (proven safe)
    rmin_s[tid] = 0xFFFFFFFFu;
    best_s[tid] = ~0ull;
  }
  if (tid < 8) tcount[tid] = 0;
  for (int i = tid; i < K_; i += 512) en_s[i] = enorm[i];

  // stage z -> f16 tile. thread: tok = tid&63, kb = (tid>>6)*4 + r.
  // global: 64 lanes read 64 consecutive floats per instr (256B coalesced).
  {
    const int tok = tid & 63;
    const int kbase = (tid >> 6) * 4;        // 8 groups x 4 kb = 32 kb
    for (int r = 0; r < 4; ++r) {
      int kb = kbase + r;
      unsigned pk[4];
#pragma unroll
      for (int j = 0; j < 4; ++j) {
        float x0 = zb[(kb * 8 + 2 * j) * HW_ + tok];
        float x1 = zb[(kb * 8 + 2 * j + 1) * HW_ + tok];
        pk[j] = f16x2pack(x0, x1);
      }
      uint4 wv; wv.x = pk[0]; wv.y = pk[1]; wv.z = pk[2]; wv.w = pk[3];
      *(uint4*)(zt + kb * 512 + tok * 8) = wv;       // 16B, conflict-free
    }
  }
  __syncthreads();

  const int lane = tid & 63;
  const int w = tid >> 6;                    // 0..7
  const int l15 = lane & 15, g = lane >> 4;
  const int cw = w * 128;                    // wave's code base (128 codes)
  const u16* Eb = E16 + (unsigned)(cw + l15) * D_ + g * 8;

  f16x8 efA[2], efB[2];
#pragma unroll
  for (int n = 0; n < 2; ++n)
    efA[n] = *(const f16x8*)(Eb + n * 16 * D_);          // prime: s=0 (ch0,kk0)

  f32x4 acc[4][2];

// one MFMA step: ef ping-pong; zf from conflict-free fp16 tile (2 b128/frag,
// consecutive 16B slots per 16-lane group). No branches/calls in the loop.
#define MSTEP(S, EFU, EFF, SN)                                                   \
  {                                                                              \
    const int kk_ = (S) & 7;                                                     \
    {                                                                            \
      const int cn_ = (SN) >> 3, kn_ = (SN) & 7;                                 \
      _Pragma("unroll")                                                          \
      for (int n = 0; n < 2; ++n)                                                \
        EFF[n] = *(const f16x8*)(Eb + (cn_ * 32 + n * 16) * D_ + kn_ * 32);      \
    }                                                                            \
    f16x8 zf_[4];                                                                \
    _Pragma("unroll")                                                            \
    for (int m = 0; m < 4; ++m)                                                  \
      zf_[m] = *(const f16x8*)(zt + (kk_ * 4 + g) * 512 + (m * 16 + l15) * 8);   \
    _Pragma("unroll")                                                            \
    for (int m = 0; m < 4; ++m)                                                  \
      _Pragma("unroll")                                                          \
      for (int n = 0; n < 2; ++n)                                                \
        acc[m][n] = __builtin_amdgcn_mfma_f32_16x16x32_f16(zf_[m], EFU[n],       \
                                                           acc[m][n], 0, 0, 0);  \
  }

  for (int s2 = 0; s2 < 32; s2 += 2) {      // 4 chunks x 8 kk
    if ((s2 & 7) == 0) {
      f32x4 z4 = {0.f, 0.f, 0.f, 0.f};
#pragma unroll
      for (int m = 0; m < 4; ++m)
#pragma unroll
        for (int n = 0; n < 2; ++n) acc[m][n] = z4;
    }
    MSTEP(s2, efA, efB, s2 + 1)
    MSTEP(s2 + 1, efB, efA, (s2 + 2) & 31)   // tail wrap value never consumed
    if ((s2 & 7) == 6) {                     // chunk end
      const int cb = cw + (s2 >> 3) * 32;
      // ph = en - 2*(A/512) = fma(-1/256, A, en); D: col=l15(code), row=g*4+r(tok)
      float enc[2];
#pragma unroll
      for (int n = 0; n < 2; ++n) enc[n] = en_s[cb + n * 16 + l15];
#pragma unroll
      for (int m = 0; m < 4; ++m)
#pragma unroll
        for (int n = 0; n < 2; ++n)
#pragma unroll
          for (int r = 0; r < 4; ++r)
            acc[m][n][r] = __builtin_fmaf(-0.00390625f, acc[m][n][r], enc[n]);
#pragma unroll
      for (int m = 0; m < 4; ++m)
#pragma unroll
        for (int r = 0; r < 4; ++r) {
          float v = fminf(acc[m][0][r], acc[m][1][r]);
          v = dppmin<0xB1>(v);     // ^1
          v = dppmin<0x4E>(v);     // ^2
          v = dppmin<0x141>(v);    // row_half_mirror
          v = dppmin<0x140>(v);    // row_mirror
          if (l15 == 0) atomicMin(&rmin_s[m * 16 + g * 4 + r], __float_as_uint(v + 4.0f));
        }
#pragma unroll
      for (int m = 0; m < 4; ++m)
#pragma unroll
        for (int r = 0; r < 4; ++r) {
          int t = m * 16 + g * 4 + r;
          float thr = (__uint_as_float(rmin_s[t]) - 4.0f) + mg_s[t];
#pragma unroll
          for (int n = 0; n < 2; ++n) {
            if (acc[m][n][r] <= thr) {
              unsigned pos = atomicAdd(&tcount[w], 1u);
              if (pos < TCAP)
                tlist[w][pos] = ((unsigned)t << 16) | (unsigned)(cb + n * 16 + l15);
            }
          }
        }
    }
  }
#undef MSTEP

  // drain own wave's triggers: exact recompute (global z + global E) -> best_s
  {
    unsigned cnt = tcount[w];
    if (cnt <= TCAP) {
      for (unsigned basei = 0; basei < cnt; basei += 64) {
        unsigned i = basei + (unsigned)lane;
        if (i < cnt) {
          unsigned e = tlist[w][i];
          exact_update(zb, E, (int)(e >> 16), (int)(e & 1023u), zn_s, en_s, best_s);
        }
      }
    } else {
      // overflow (astronomically rare): exact-verify wave's whole 64x128 tile
      for (unsigned i = (unsigned)lane; i < 64u * 128u; i += 64) {
        exact_update(zb, E, (int)(i >> 7), cw + (int)(i & 127u), zn_s, en_s, best_s);
      }
    }
  }
  __syncthreads();   // best_s final

  // ---------------- phase B: d-major scatter, no LDS staging ----------------
  if (tid < 64) {
    int k = (int)(best_s[tid] & 1023ull);
    out_idx[n0 + tid] = (float)k;
    atomicAdd(&counts[k], 1.0f);
  }
  // lane = token; wave w handles d in [w*32, w*32+32). All z/zq accesses are
  // 64-lane 256B coalesced; E/embsum are per-lane scalar (L2).
  {
    const int myk = (int)(best_s[lane] & 1023ull);
    const float* Er = E + myk * D_;
    float* es = embsum + myk * D_;
    float* ob = out_zq + bimg * (D_ * HW_) + hw0;
    float lsum = 0.f;
    for (int dd = 0; dd < 32; ++dd) {
      int d = w * 32 + dd;
      float zv = zb[d * HW_ + lane];
      float e = Er[d];
      float df = __fsub_rn(zv, e);
      lsum += df * df;
      ob[d * HW_ + lane] = __fadd_rn(zv, __fsub_rn(e, zv));  // ref: z + (z_q - z)
      atomicAdd(es + d, zv);
    }
#pragma unroll
    for (int o = 32; o > 0; o >>= 1) lsum += __shfl_down(lsum, o, 64);
    if (lane == 0) wred[w] = lsum;
  }
  __syncthreads();
  if (tid == 0) {
    float s = ((wred[0] + wred[1]) + (wred[2] + wred[3])) +
              ((wred[4] + wred[5]) + (wred[6] + wred[7]));
    atomicAdd(loss_sum, s);
  }
}

// ---------------- EMA cluster-size + n + loss finalize ----------------
__global__ void vq_newcs_v7(const float* __restrict__ cs_in, const float* __restrict__ counts,
                            float* __restrict__ newcs, float* __restrict__ nsum,
                            const float* __restrict__ loss_sum,
                            float* __restrict__ out_loss, float* __restrict__ out_ncs) {
  int k = blockIdx.x * 256 + threadIdx.x;
  float v = __fadd_rn(__fmul_rn(0.99f, cs_in[k]), __fmul_rn(0.01f, counts[k]));
  newcs[k] = v;
  out_ncs[k] = v;
  float s = v;
#pragma unroll
  for (int o = 32; o > 0; o >>= 1) s += __shfl_down(s, o, 64);
  __shared__ float w[4];
  if ((threadIdx.x & 63) == 0) w[threadIdx.x >> 6] = s;
  __syncthreads();
  if (threadIdx.x == 0) atomicAdd(nsum, w[0] + w[1] + w[2] + w[3]);
  if (k == 0) out_loss[0] = loss_sum[0] * (1.0f / 8388608.0f);
}

// ---------------- new_es + new_embedding ----------------
__global__ void vq_newemb_v7(const float* __restrict__ es_in, const float* __restrict__ embsum,
                             const float* __restrict__ newcs, const float* __restrict__ nsum,
                             float* __restrict__ out_emb, float* __restrict__ out_nes) {
  int k = blockIdx.x, d = threadIdx.x;
  float n = *nsum;
  float cs = (newcs[k] + 1e-5f) / (n + 1024.0f * 1e-5f) * n;   // ref formula order
  float es = __fadd_rn(__fmul_rn(0.99f, es_in[k * D_ + d]),
                       __fmul_rn(0.01f, embsum[k * D_ + d]));
  out_nes[k * D_ + d] = es;
  out_emb[k * D_ + d] = es / cs;
}

extern "C" void kernel_launch(void* const* d_in, const int* in_sizes, int n_in,
                              void* d_out, int out_size, void* d_ws, size_t ws_size,
                              hipStream_t stream) {
  (void)in_sizes; (void)n_in; (void)out_size; (void)ws_size;
  const float* z       = (const float*)d_in[0];
  const float* E       = (const float*)d_in[1];
  const float* ema_cs  = (const float*)d_in[2];
  const float* ema_es  = (const float*)d_in[3];
  float* out = (float*)d_out;
  char* ws = (char*)d_ws;
  float* counts = (float*)(ws + WS_COUNTS);
  float* embsum = (float*)(ws + WS_EMBSUM);
  float* loss_s = (float*)(ws + WS_LOSS);
  float* nsum   = (float*)(ws + WS_NSUM);
  unsigned* enmax = (unsigned*)(ws + WS_ENMAX);
  float* newcs  = (float*)(ws + WS_NEWCS);
  float* enorm  = (float*)(ws + WS_ENORM);
  u16*   e16    = (u16*)(ws + WS_E16);

  hipMemsetAsync(ws + WS_ZERO0, 0, WS_ZEROLEN, stream);   // counts/embsum/loss/nsum/enmax
  vq_eprep<<<dim3(32), dim3(256), 0, stream>>>(E, enorm, e16, enmax);
  vq_main<<<dim3(512), dim3(512), 0, stream>>>(z, E, e16, enorm, enmax,
                                               embsum, loss_s, counts,
                                               out + O_ZQ, out + O_IDX);
  vq_newcs_v7<<<dim3(4), dim3(256), 0, stream>>>(ema_cs, counts, newcs, nsum, loss_s,
                                                 out + O_LOSS, out + O_NCS);
  vq_newemb_v7<<<dim3(K_), dim3(256), 0, stream>>>(ema_es, embsum, newcs, nsum,
                                                   out + O_EMB, out + O_NES);
}